// Round 1
// baseline (765.553 us; speedup 1.0000x reference)
//
#include <hip/hip_runtime.h>
#include <hip/hip_bf16.h>

#define T_SEQ 2048
#define HIDDEN_SZ 4096
#define NUM_HEADS 32
#define HEAD_DIM 128
#define KV_GROUPS 2
#define Q_SZ 4096          // NUM_HEADS*HEAD_DIM
#define KV_SZ 256          // KV_GROUPS*HEAD_DIM
#define QKV_DIM 4608       // Q_SZ + 2*KV_SZ

typedef __attribute__((ext_vector_type(8))) short bf16x8_t;   // 8 bf16 = 4 VGPR (A/B frag)
typedef __attribute__((ext_vector_type(4))) float f32x4_t;    // C/D frag

__device__ inline void store_c(float* p, float v) { *p = v; }
__device__ inline void store_c(__hip_bfloat16* p, float v) { *p = __float2bfloat16(v); }

// ---------------- fp32 -> bf16 contiguous convert ----------------
__global__ __launch_bounds__(256) void convert_bf16_kernel(const float* __restrict__ in,
                                                           __hip_bfloat16* __restrict__ out,
                                                           int n) {
    int i = (blockIdx.x * 256 + threadIdx.x) * 4;
    if (i + 3 < n) {
        float4 v = *reinterpret_cast<const float4*>(in + i);
        alignas(8) __hip_bfloat16 tmp[4] = {__float2bfloat16(v.x), __float2bfloat16(v.y),
                                            __float2bfloat16(v.z), __float2bfloat16(v.w)};
        *reinterpret_cast<ushort4*>(out + i) = *reinterpret_cast<const ushort4*>(tmp);
    }
}

// ---------------- fp32 [R][C] -> bf16 [C][R] tile transpose ----------------
__global__ __launch_bounds__(256) void transpose_convert_kernel(const float* __restrict__ in,
                                                                __hip_bfloat16* __restrict__ out,
                                                                int R, int C) {
    __shared__ float tile[32][33];
    const int tx = threadIdx.x;   // 0..31
    const int ty = threadIdx.y;   // 0..7
    const int c0 = blockIdx.x * 32, r0 = blockIdx.y * 32;
    #pragma unroll
    for (int i = 0; i < 4; ++i)
        tile[ty + i * 8][tx] = in[(size_t)(r0 + ty + i * 8) * C + c0 + tx];
    __syncthreads();
    #pragma unroll
    for (int i = 0; i < 4; ++i)
        out[(size_t)(c0 + ty + i * 8) * R + r0 + tx] = __float2bfloat16(tile[tx][ty + i * 8]);
}

// ---------------- bf16 MFMA GEMM: C[M][N] = A[M][K] * BT[N][K]^T (+bias) ----------------
// 128x128 block tile, 4 waves (2x2), each wave 64x64 = 4x4 accums of 16x16, BK=32.
template <typename OutT>
__global__ __launch_bounds__(256) void gemm_bf16_kernel(const __hip_bfloat16* __restrict__ A,
                                                        const __hip_bfloat16* __restrict__ BT,
                                                        const float* __restrict__ bias,
                                                        OutT* __restrict__ C,
                                                        int M, int N, int K) {
    constexpr int BM = 128, BN = 128, BK = 32, LSTR = 40; // 40 elems = 80B row stride (16B-aligned, bank-friendly)
    __shared__ __hip_bfloat16 lA[BM * LSTR];
    __shared__ __hip_bfloat16 lB[BN * LSTR];
    const int tid = threadIdx.x;
    const int bm = blockIdx.y * BM, bn = blockIdx.x * BN;
    const int wave = tid >> 6, lane = tid & 63;
    const int wr = wave >> 1, wc = wave & 1;
    const int n16 = lane & 15, quad = lane >> 4;
    f32x4_t acc[4][4] = {};
    for (int kk = 0; kk < K; kk += BK) {
        #pragma unroll
        for (int r = 0; r < 2; ++r) {
            int c = r * 256 + tid;      // chunk of 8 bf16
            int row = c >> 2;           // 0..127
            int col = (c & 3) * 8;      // 0,8,16,24
            *reinterpret_cast<uint4*>(&lA[row * LSTR + col]) =
                *reinterpret_cast<const uint4*>(&A[(size_t)(bm + row) * K + kk + col]);
            *reinterpret_cast<uint4*>(&lB[row * LSTR + col]) =
                *reinterpret_cast<const uint4*>(&BT[(size_t)(bn + row) * K + kk + col]);
        }
        __syncthreads();
        bf16x8_t af[4], bfr[4];
        #pragma unroll
        for (int i = 0; i < 4; ++i)
            af[i] = *reinterpret_cast<const bf16x8_t*>(&lA[(wr * 64 + i * 16 + n16) * LSTR + quad * 8]);
        #pragma unroll
        for (int j = 0; j < 4; ++j)
            bfr[j] = *reinterpret_cast<const bf16x8_t*>(&lB[(wc * 64 + j * 16 + n16) * LSTR + quad * 8]);
        #pragma unroll
        for (int i = 0; i < 4; ++i)
            #pragma unroll
            for (int j = 0; j < 4; ++j)
                acc[i][j] = __builtin_amdgcn_mfma_f32_16x16x32_bf16(af[i], bfr[j], acc[i][j], 0, 0, 0);
        __syncthreads();
    }
    #pragma unroll
    for (int i = 0; i < 4; ++i) {
        #pragma unroll
        for (int j = 0; j < 4; ++j) {
            int col = bn + wc * 64 + j * 16 + n16;
            float bv = bias ? bias[col] : 0.0f;
            #pragma unroll
            for (int r = 0; r < 4; ++r) {
                int row = bm + wr * 64 + i * 16 + quad * 4 + r;   // C/D: col=lane&15, row=quad*4+reg
                store_c(&C[(size_t)row * N + col], acc[i][j][r] + bv);
            }
        }
    }
}

// ---------------- RoPE + relayout: qkv[t][4608] -> q[h][t][d], k[g][t][d], vT[g][d][t] ----------------
__global__ __launch_bounds__(64) void rope_reorg_kernel(const __hip_bfloat16* __restrict__ qkv,
                                                        const int* __restrict__ positions,
                                                        __hip_bfloat16* __restrict__ qo,
                                                        __hip_bfloat16* __restrict__ ko,
                                                        __hip_bfloat16* __restrict__ vTo) {
    const int t = blockIdx.x;
    const int u = blockIdx.y;       // 0..31 q heads, 32..33 k groups, 34..35 v groups
    const int tid = threadIdx.x;    // 0..63, handles dims (2*tid, 2*tid+1)
    const int d0 = tid * 2, d1 = d0 + 1;
    int col;
    if (u < 32) col = u * HEAD_DIM;
    else if (u < 34) col = Q_SZ + (u - 32) * HEAD_DIM;
    else col = Q_SZ + KV_SZ + (u - 34) * HEAD_DIM;
    float x0 = __bfloat162float(qkv[(size_t)t * QKV_DIM + col + d0]);
    float x1 = __bfloat162float(qkv[(size_t)t * QKV_DIM + col + d1]);
    float o0 = x0, o1 = x1;
    if (u < 34 && tid < 32) {  // rot_dim = 64: pairs i=0..31; dims 64..127 pass through
        float pos = (float)positions[t];
        // theta_i = 10000^(-i/32) = 2^(-i * log2(10000)/32)
        float theta = exp2f(-(float)tid * 0.4152410118609203f);
        float ang = pos * theta;
        float sn, cs;
        sincosf(ang, &sn, &cs);
        o0 = x0 * cs - x1 * sn;
        o1 = x1 * cs + x0 * sn;
    }
    if (u < 32) {
        __hip_bfloat16* dst = qo + ((size_t)u * T_SEQ + t) * HEAD_DIM;
        dst[d0] = __float2bfloat16(o0);
        dst[d1] = __float2bfloat16(o1);
    } else if (u < 34) {
        __hip_bfloat16* dst = ko + ((size_t)(u - 32) * T_SEQ + t) * HEAD_DIM;
        dst[d0] = __float2bfloat16(o0);
        dst[d1] = __float2bfloat16(o1);
    } else {
        int gg = u - 34;
        vTo[((size_t)gg * HEAD_DIM + d0) * T_SEQ + t] = __float2bfloat16(o0);
        vTo[((size_t)gg * HEAD_DIM + d1) * T_SEQ + t] = __float2bfloat16(o1);
    }
}

// ---------------- causal GQA flash attention ----------------
// 1 wave per (head, 32 q-rows). QK^T + online softmax + PV, all 16x16x32 MFMA.
__global__ __launch_bounds__(64) void flash_attn_kernel(const __hip_bfloat16* __restrict__ q,
                                                        const __hip_bfloat16* __restrict__ k,
                                                        const __hip_bfloat16* __restrict__ vT,
                                                        __hip_bfloat16* __restrict__ ctx) {
    const int qb = blockIdx.x;          // 0..63 (32 rows each)
    const int h = blockIdx.y;           // 0..31
    const int g = h >> 4;               // head -> kv group (32/2 = 16 heads per group)
    const int lane = threadIdx.x;
    const int n16 = lane & 15, quad = lane >> 4;
    __shared__ __hip_bfloat16 pl[32 * 40];   // P tile: [32 rows][32 keys], stride 40 (80B, aligned)

    // Q fragments: A-layout A[m=lane&15][k=quad*8+j]; 2 row-tiles x 4 d-frags (K=32 each)
    bf16x8_t qf[2][4];
    #pragma unroll
    for (int rt = 0; rt < 2; ++rt)
        #pragma unroll
        for (int f = 0; f < 4; ++f)
            qf[rt][f] = *reinterpret_cast<const bf16x8_t*>(
                q + ((size_t)h * T_SEQ + qb * 32 + rt * 16 + n16) * HEAD_DIM + f * 32 + quad * 8);

    f32x4_t accO[2][8] = {};
    float m_[2][4], l_[2][4];
    #pragma unroll
    for (int rt = 0; rt < 2; ++rt)
        #pragma unroll
        for (int r = 0; r < 4; ++r) { m_[rt][r] = -1e30f; l_[rt][r] = 0.0f; }

    for (int kt = 0; kt <= qb; ++kt) {
        // K fragments: B-layout B[n=key][k=d], K rows are d-contiguous in memory
        bf16x8_t kf[2][4];
        #pragma unroll
        for (int c = 0; c < 2; ++c)
            #pragma unroll
            for (int f = 0; f < 4; ++f)
                kf[c][f] = *reinterpret_cast<const bf16x8_t*>(
                    k + ((size_t)g * T_SEQ + kt * 32 + c * 16 + n16) * HEAD_DIM + f * 32 + quad * 8);
        f32x4_t s[2][2] = {};
        #pragma unroll
        for (int rt = 0; rt < 2; ++rt)
            #pragma unroll
            for (int c = 0; c < 2; ++c)
                #pragma unroll
                for (int f = 0; f < 4; ++f)
                    s[rt][c] = __builtin_amdgcn_mfma_f32_16x16x32_bf16(qf[rt][f], kf[c][f], s[rt][c], 0, 0, 0);

        const float scale = 0.08838834764831845f;  // 1/sqrt(128)
        const bool diag = (kt == qb);
        #pragma unroll
        for (int rt = 0; rt < 2; ++rt) {
            float sv[2][4];
            #pragma unroll
            for (int c = 0; c < 2; ++c)
                #pragma unroll
                for (int r = 0; r < 4; ++r) {
                    float v = s[rt][c][r] * scale;
                    if (diag && (c * 16 + n16 > rt * 16 + quad * 4 + r)) v = -1e30f;
                    sv[c][r] = v;
                }
            // row max over the 16 lanes holding this row's columns
            float rm[4];
            #pragma unroll
            for (int r = 0; r < 4; ++r) rm[r] = fmaxf(sv[0][r], sv[1][r]);
            #pragma unroll
            for (int d = 1; d < 16; d <<= 1)
                #pragma unroll
                for (int r = 0; r < 4; ++r) rm[r] = fmaxf(rm[r], __shfl_xor(rm[r], d, 64));
            float alpha[4];
            #pragma unroll
            for (int r = 0; r < 4; ++r) {
                float mn = fmaxf(m_[rt][r], rm[r]);
                alpha[r] = __expf(m_[rt][r] - mn);
                m_[rt][r] = mn;
            }
            #pragma unroll
            for (int c = 0; c < 2; ++c)
                #pragma unroll
                for (int r = 0; r < 4; ++r) sv[c][r] = __expf(sv[c][r] - m_[rt][r]);
            float rs[4];
            #pragma unroll
            for (int r = 0; r < 4; ++r) rs[r] = sv[0][r] + sv[1][r];
            #pragma unroll
            for (int d = 1; d < 16; d <<= 1)
                #pragma unroll
                for (int r = 0; r < 4; ++r) rs[r] += __shfl_xor(rs[r], d, 64);
            #pragma unroll
            for (int r = 0; r < 4; ++r) l_[rt][r] = l_[rt][r] * alpha[r] + rs[r];
            #pragma unroll
            for (int dt = 0; dt < 8; ++dt)
                #pragma unroll
                for (int r = 0; r < 4; ++r) accO[rt][dt][r] *= alpha[r];
            // P (C-layout) -> LDS for the C->A layout transform
            #pragma unroll
            for (int c = 0; c < 2; ++c)
                #pragma unroll
                for (int r = 0; r < 4; ++r)
                    pl[(rt * 16 + quad * 4 + r) * 40 + c * 16 + n16] = __float2bfloat16(sv[c][r]);
        }
        __syncthreads();
        bf16x8_t pa[2];
        #pragma unroll
        for (int rt = 0; rt < 2; ++rt)
            pa[rt] = *reinterpret_cast<const bf16x8_t*>(&pl[(rt * 16 + n16) * 40 + quad * 8]);
        #pragma unroll
        for (int dt = 0; dt < 8; ++dt) {
            // V B-frag: B[n=d][k=key] from vT[g][d][t] (key-contiguous)
            bf16x8_t vf = *reinterpret_cast<const bf16x8_t*>(
                vT + ((size_t)g * HEAD_DIM + dt * 16 + n16) * T_SEQ + kt * 32 + quad * 8);
            #pragma unroll
            for (int rt = 0; rt < 2; ++rt)
                accO[rt][dt] = __builtin_amdgcn_mfma_f32_16x16x32_bf16(pa[rt], vf, accO[rt][dt], 0, 0, 0);
        }
        __syncthreads();
    }
    #pragma unroll
    for (int rt = 0; rt < 2; ++rt) {
        float inv[4];
        #pragma unroll
        for (int r = 0; r < 4; ++r) inv[r] = 1.0f / l_[rt][r];
        #pragma unroll
        for (int dt = 0; dt < 8; ++dt)
            #pragma unroll
            for (int r = 0; r < 4; ++r) {
                int t = qb * 32 + rt * 16 + quad * 4 + r;
                int col = h * HEAD_DIM + dt * 16 + n16;
                ctx[(size_t)t * Q_SZ + col] = __float2bfloat16(accO[rt][dt][r] * inv[r]);
            }
    }
}

extern "C" void kernel_launch(void* const* d_in, const int* in_sizes, int n_in,
                              void* d_out, int out_size, void* d_ws, size_t ws_size,
                              hipStream_t stream) {
    (void)in_sizes; (void)n_in; (void)out_size; (void)ws_size;
    const int*   positions = (const int*)d_in[0];
    const float* hidden    = (const float*)d_in[1];
    const float* w_qkv     = (const float*)d_in[2];
    const float* b_qkv     = (const float*)d_in[3];
    const float* w_dense   = (const float*)d_in[4];
    float* out = (float*)d_out;

    char* ws = (char*)d_ws;
    __hip_bfloat16* h_bf   = (__hip_bfloat16*)ws; ws += (size_t)T_SEQ * HIDDEN_SZ * 2;   // 16.8 MB (aliased by ctx later)
    __hip_bfloat16* wqkvT  = (__hip_bfloat16*)ws; ws += (size_t)QKV_DIM * HIDDEN_SZ * 2; // 37.7 MB
    __hip_bfloat16* wdT    = (__hip_bfloat16*)ws; ws += (size_t)HIDDEN_SZ * HIDDEN_SZ * 2; // 33.6 MB
    __hip_bfloat16* qkv_bf = (__hip_bfloat16*)ws; ws += (size_t)T_SEQ * QKV_DIM * 2;     // 18.9 MB
    __hip_bfloat16* q_bf   = (__hip_bfloat16*)ws; ws += (size_t)NUM_HEADS * T_SEQ * HEAD_DIM * 2; // 16.8 MB
    __hip_bfloat16* k_bf   = (__hip_bfloat16*)ws; ws += (size_t)KV_GROUPS * T_SEQ * HEAD_DIM * 2; // 1 MB
    __hip_bfloat16* vT_bf  = (__hip_bfloat16*)ws; ws += (size_t)KV_GROUPS * HEAD_DIM * T_SEQ * 2; // 1 MB
    __hip_bfloat16* ctx_bf = h_bf;  // h_bf dead after QKV GEMM; reuse for ctx (same 16.8 MB size)

    // 1) hidden fp32 -> bf16
    convert_bf16_kernel<<<(T_SEQ * HIDDEN_SZ) / (256 * 4), 256, 0, stream>>>(hidden, h_bf, T_SEQ * HIDDEN_SZ);
    // 2) weights fp32 [K][N] -> bf16 [N][K]
    transpose_convert_kernel<<<dim3(QKV_DIM / 32, HIDDEN_SZ / 32), dim3(32, 8), 0, stream>>>(w_qkv, wqkvT, HIDDEN_SZ, QKV_DIM);
    transpose_convert_kernel<<<dim3(HIDDEN_SZ / 32, HIDDEN_SZ / 32), dim3(32, 8), 0, stream>>>(w_dense, wdT, HIDDEN_SZ, HIDDEN_SZ);
    // 3) QKV GEMM (+bias) -> bf16 qkv
    gemm_bf16_kernel<__hip_bfloat16><<<dim3(QKV_DIM / 128, T_SEQ / 128), 256, 0, stream>>>(
        h_bf, wqkvT, b_qkv, qkv_bf, T_SEQ, QKV_DIM, HIDDEN_SZ);
    // 4) RoPE + relayout
    rope_reorg_kernel<<<dim3(T_SEQ, NUM_HEADS + 2 * KV_GROUPS), 64, 0, stream>>>(
        qkv_bf, positions, q_bf, k_bf, vT_bf);
    // 5) causal GQA flash attention -> ctx bf16 [t][h*128+d]
    flash_attn_kernel<<<dim3(T_SEQ / 32, NUM_HEADS), 64, 0, stream>>>(q_bf, k_bf, vT_bf, ctx_bf);
    // 6) dense GEMM -> fp32 out
    gemm_bf16_kernel<float><<<dim3(HIDDEN_SZ / 128, T_SEQ / 128), 256, 0, stream>>>(
        ctx_bf, wdT, nullptr, out, T_SEQ, HIDDEN_SZ, HIDDEN_SZ);
}

// Round 2
// 752.030 us; speedup vs baseline: 1.0180x; 1.0180x over previous
//
#include <hip/hip_runtime.h>
#include <hip/hip_bf16.h>

#define T_SEQ 2048
#define HIDDEN_SZ 4096
#define NUM_HEADS 32
#define HEAD_DIM 128
#define KV_GROUPS 2
#define Q_SZ 4096          // NUM_HEADS*HEAD_DIM
#define KV_SZ 256          // KV_GROUPS*HEAD_DIM
#define QKV_DIM 4608       // Q_SZ + 2*KV_SZ

typedef __attribute__((ext_vector_type(8))) short bf16x8_t;   // 8 bf16 = 4 VGPR (A/B frag)
typedef __attribute__((ext_vector_type(4))) float f32x4_t;    // C/D frag

__device__ inline void store_c(float* p, float v) { *p = v; }
__device__ inline void store_c(__hip_bfloat16* p, float v) { *p = __float2bfloat16(v); }

// async global->LDS, 16B per lane; LDS dest = wave-uniform base + lane*16
#define GLDS16(gp, lp)                                                                  \
    __builtin_amdgcn_global_load_lds((const __attribute__((address_space(1))) unsigned int*)(gp), \
                                     (__attribute__((address_space(3))) unsigned int*)(lp), 16, 0, 0)

// ---------------- fp32 -> bf16 contiguous convert ----------------
__global__ __launch_bounds__(256) void convert_bf16_kernel(const float* __restrict__ in,
                                                           __hip_bfloat16* __restrict__ out,
                                                           int n) {
    int i = (blockIdx.x * 256 + threadIdx.x) * 4;
    if (i + 3 < n) {
        float4 v = *reinterpret_cast<const float4*>(in + i);
        alignas(8) __hip_bfloat16 tmp[4] = {__float2bfloat16(v.x), __float2bfloat16(v.y),
                                            __float2bfloat16(v.z), __float2bfloat16(v.w)};
        *reinterpret_cast<ushort4*>(out + i) = *reinterpret_cast<const ushort4*>(tmp);
    }
}

// ---------------- fp32 [R][C] -> bf16 [C][R] tile transpose ----------------
__global__ __launch_bounds__(256) void transpose_convert_kernel(const float* __restrict__ in,
                                                                __hip_bfloat16* __restrict__ out,
                                                                int R, int C) {
    __shared__ float tile[32][33];
    const int tx = threadIdx.x;   // 0..31
    const int ty = threadIdx.y;   // 0..7
    const int c0 = blockIdx.x * 32, r0 = blockIdx.y * 32;
    #pragma unroll
    for (int i = 0; i < 4; ++i)
        tile[ty + i * 8][tx] = in[(size_t)(r0 + ty + i * 8) * C + c0 + tx];
    __syncthreads();
    #pragma unroll
    for (int i = 0; i < 4; ++i)
        out[(size_t)(c0 + ty + i * 8) * R + r0 + tx] = __float2bfloat16(tile[tx][ty + i * 8]);
}

// ---------------- bf16 MFMA GEMM: C[M][N] = A[M][K] * BT[N][K]^T (+bias) ----------------
// 128x128 block tile, 4 waves (2x2), each wave 64x64 = 4x4 accums of 16x16, BK=32.
// m97 structure: global_load_lds width-16 staging into UNPADDED stride-32 LDS tiles.
template <typename OutT>
__global__ __launch_bounds__(256) void gemm_bf16_kernel(const __hip_bfloat16* __restrict__ A,
                                                        const __hip_bfloat16* __restrict__ BT,
                                                        const float* __restrict__ bias,
                                                        OutT* __restrict__ C,
                                                        int M, int N, int K) {
    constexpr int BM = 128, BN = 128, BK = 32;
    __shared__ __hip_bfloat16 lA[BM * BK];   // packed: row*32 + col (no pad — global_load_lds order)
    __shared__ __hip_bfloat16 lB[BN * BK];
    const int tid = threadIdx.x;
    const int bm = blockIdx.y * BM, bn = blockIdx.x * BN;
    const int wave = tid >> 6, lane = tid & 63;
    const int wr = wave >> 1, wc = wave & 1;
    const int n16 = lane & 15, quad = lane >> 4;
    const int lrow = lane >> 2;          // 0..15 within a 16-row chunk
    const int lcol = (lane & 3) * 8;     // elem col 0,8,16,24
    f32x4_t acc[4][4] = {};
    for (int kk = 0; kk < K; kk += BK) {
        // staging: 8 chunks of 1 KiB (16 rows x 64 B) per tile, 2 chunks per wave per tile
        #pragma unroll
        for (int p = 0; p < 2; ++p) {
            int ca = wave * 2 + p;                 // chunk 0..7
            int row = ca * 16 + lrow;
            GLDS16(&A[(size_t)(bm + row) * K + kk + lcol], &lA[ca * 512]);
            GLDS16(&BT[(size_t)(bn + row) * K + kk + lcol], &lB[ca * 512]);
        }
        __syncthreads();   // compiler emits vmcnt(0) drain before barrier
        bf16x8_t af[4], bfr[4];
        #pragma unroll
        for (int i = 0; i < 4; ++i)
            af[i] = *reinterpret_cast<const bf16x8_t*>(&lA[(wr * 64 + i * 16 + n16) * BK + quad * 8]);
        #pragma unroll
        for (int j = 0; j < 4; ++j)
            bfr[j] = *reinterpret_cast<const bf16x8_t*>(&lB[(wc * 64 + j * 16 + n16) * BK + quad * 8]);
        #pragma unroll
        for (int i = 0; i < 4; ++i)
            #pragma unroll
            for (int j = 0; j < 4; ++j)
                acc[i][j] = __builtin_amdgcn_mfma_f32_16x16x32_bf16(af[i], bfr[j], acc[i][j], 0, 0, 0);
        __syncthreads();
    }
    #pragma unroll
    for (int i = 0; i < 4; ++i) {
        #pragma unroll
        for (int j = 0; j < 4; ++j) {
            int col = bn + wc * 64 + j * 16 + n16;
            float bv = bias ? bias[col] : 0.0f;
            #pragma unroll
            for (int r = 0; r < 4; ++r) {
                int row = bm + wr * 64 + i * 16 + quad * 4 + r;   // C/D: col=lane&15, row=quad*4+reg
                store_c(&C[(size_t)row * N + col], acc[i][j][r] + bv);
            }
        }
    }
}

// ---------------- RoPE + relayout: qkv[t][4608] -> q[h][t][d], k[g][t][d], vT[g][d][t] ----------------
// Q is pre-scaled by (1/sqrt(128))*log2(e) so flash attention can use raw exp2.
__global__ __launch_bounds__(64) void rope_reorg_kernel(const __hip_bfloat16* __restrict__ qkv,
                                                        const int* __restrict__ positions,
                                                        __hip_bfloat16* __restrict__ qo,
                                                        __hip_bfloat16* __restrict__ ko,
                                                        __hip_bfloat16* __restrict__ vTo) {
    const int t = blockIdx.x;
    const int u = blockIdx.y;       // 0..31 q heads, 32..33 k groups, 34..35 v groups
    const int tid = threadIdx.x;    // 0..63, handles dims (2*tid, 2*tid+1)
    const int d0 = tid * 2, d1 = d0 + 1;
    int col;
    if (u < 32) col = u * HEAD_DIM;
    else if (u < 34) col = Q_SZ + (u - 32) * HEAD_DIM;
    else col = Q_SZ + KV_SZ + (u - 34) * HEAD_DIM;
    float x0 = __bfloat162float(qkv[(size_t)t * QKV_DIM + col + d0]);
    float x1 = __bfloat162float(qkv[(size_t)t * QKV_DIM + col + d1]);
    float o0 = x0, o1 = x1;
    if (u < 34 && tid < 32) {  // rot_dim = 64: pairs i=0..31; dims 64..127 pass through
        float pos = (float)positions[t];
        // theta_i = 10000^(-i/32) = 2^(-i * log2(10000)/32)
        float theta = exp2f(-(float)tid * 0.4152410118609203f);
        float ang = pos * theta;
        float sn, cs;
        sincosf(ang, &sn, &cs);
        o0 = x0 * cs - x1 * sn;
        o1 = x1 * cs + x0 * sn;
    }
    if (u < 32) {
        constexpr float qscale = 0.08838834764831845f * 1.4426950408889634f;  // rsqrt(128)*log2e
        __hip_bfloat16* dst = qo + ((size_t)u * T_SEQ + t) * HEAD_DIM;
        dst[d0] = __float2bfloat16(o0 * qscale);
        dst[d1] = __float2bfloat16(o1 * qscale);
    } else if (u < 34) {
        __hip_bfloat16* dst = ko + ((size_t)(u - 32) * T_SEQ + t) * HEAD_DIM;
        dst[d0] = __float2bfloat16(o0);
        dst[d1] = __float2bfloat16(o1);
    } else {
        int gg = u - 34;
        vTo[((size_t)gg * HEAD_DIM + d0) * T_SEQ + t] = __float2bfloat16(o0);
        vTo[((size_t)gg * HEAD_DIM + d1) * T_SEQ + t] = __float2bfloat16(o1);
    }
}

// ---------------- causal GQA flash attention ----------------
// 4 independent waves per block (no barriers), each wave owns 32 q-rows.
// Reversed q-block order so longest waves launch first. K-frag ping-pong prefetch.
// Scores arrive pre-scaled into log2 domain (Q folded), so softmax uses raw exp2.
__global__ __launch_bounds__(256, 2) void flash_attn_kernel(const __hip_bfloat16* __restrict__ q,
                                                            const __hip_bfloat16* __restrict__ k,
                                                            const __hip_bfloat16* __restrict__ vT,
                                                            __hip_bfloat16* __restrict__ ctx) {
    const int qblk = (int)gridDim.x - 1 - (int)blockIdx.x;   // reversed: big blocks first
    const int h = blockIdx.y;           // 0..31
    const int g = h >> 4;               // head -> kv group (16 heads per group)
    const int wave = threadIdx.x >> 6;
    const int lane = threadIdx.x & 63;
    const int n16 = lane & 15, quad = lane >> 4;
    const int qrow0 = qblk * 128 + wave * 32;
    const int ktmax = qrow0 >> 5;       // diag tile index (qrow0 is a multiple of 32)
    __shared__ __hip_bfloat16 pl_all[4 * 32 * 40];
    __hip_bfloat16* pl = pl_all + wave * 32 * 40;   // per-wave region; intra-wave LDS is in-order

    // Q fragments: A-layout A[m=lane&15][k=quad*8+j]; 2 row-tiles x 4 d-frags (K=32 each)
    bf16x8_t qf[2][4];
    #pragma unroll
    for (int rt = 0; rt < 2; ++rt)
        #pragma unroll
        for (int f = 0; f < 4; ++f)
            qf[rt][f] = *reinterpret_cast<const bf16x8_t*>(
                q + ((size_t)h * T_SEQ + qrow0 + rt * 16 + n16) * HEAD_DIM + f * 32 + quad * 8);

    f32x4_t accO[2][8] = {};
    float m_[2][4], l_[2][4];
    #pragma unroll
    for (int rt = 0; rt < 2; ++rt)
        #pragma unroll
        for (int r = 0; r < 4; ++r) { m_[rt][r] = -1e30f; l_[rt][r] = 0.0f; }

    auto load_k = [&](bf16x8_t kf[2][4], int kt) {
        #pragma unroll
        for (int c = 0; c < 2; ++c)
            #pragma unroll
            for (int f = 0; f < 4; ++f)
                kf[c][f] = *reinterpret_cast<const bf16x8_t*>(
                    k + ((size_t)g * T_SEQ + kt * 32 + c * 16 + n16) * HEAD_DIM + f * 32 + quad * 8);
    };

    auto iter_body = [&](int kt, bf16x8_t kf[2][4]) {
        // V frags issued first: B[n=d][k=key] from vT[g][d][t]; overlap QK+softmax
        bf16x8_t vf[8];
        #pragma unroll
        for (int dt = 0; dt < 8; ++dt)
            vf[dt] = *reinterpret_cast<const bf16x8_t*>(
                vT + ((size_t)g * HEAD_DIM + dt * 16 + n16) * T_SEQ + kt * 32 + quad * 8);
        f32x4_t s[2][2] = {};
        #pragma unroll
        for (int rt = 0; rt < 2; ++rt)
            #pragma unroll
            for (int c = 0; c < 2; ++c)
                #pragma unroll
                for (int f = 0; f < 4; ++f)
                    s[rt][c] = __builtin_amdgcn_mfma_f32_16x16x32_bf16(qf[rt][f], kf[c][f], s[rt][c], 0, 0, 0);
        const bool diag = (kt == ktmax);
        #pragma unroll
        for (int rt = 0; rt < 2; ++rt) {
            float sv[2][4];
            #pragma unroll
            for (int c = 0; c < 2; ++c)
                #pragma unroll
                for (int r = 0; r < 4; ++r) {
                    float v = s[rt][c][r];   // already scaled & in log2 domain (Q folding)
                    if (diag && (c * 16 + n16 > rt * 16 + quad * 4 + r)) v = -1e30f;
                    sv[c][r] = v;
                }
            float rm[4];
            #pragma unroll
            for (int r = 0; r < 4; ++r) rm[r] = fmaxf(sv[0][r], sv[1][r]);
            #pragma unroll
            for (int d = 1; d < 16; d <<= 1)
                #pragma unroll
                for (int r = 0; r < 4; ++r) rm[r] = fmaxf(rm[r], __shfl_xor(rm[r], d, 64));
            float alpha[4];
            #pragma unroll
            for (int r = 0; r < 4; ++r) {
                float mn = fmaxf(m_[rt][r], rm[r]);
                alpha[r] = __builtin_amdgcn_exp2f(m_[rt][r] - mn);
                m_[rt][r] = mn;
            }
            #pragma unroll
            for (int c = 0; c < 2; ++c)
                #pragma unroll
                for (int r = 0; r < 4; ++r) sv[c][r] = __builtin_amdgcn_exp2f(sv[c][r] - m_[rt][r]);
            float rs[4];
            #pragma unroll
            for (int r = 0; r < 4; ++r) rs[r] = sv[0][r] + sv[1][r];
            #pragma unroll
            for (int d = 1; d < 16; d <<= 1)
                #pragma unroll
                for (int r = 0; r < 4; ++r) rs[r] += __shfl_xor(rs[r], d, 64);
            #pragma unroll
            for (int r = 0; r < 4; ++r) l_[rt][r] = l_[rt][r] * alpha[r] + rs[r];
            // skip the 32-mult rescale when no row's max moved (common after warm-up)
            bool upd = (alpha[0] < 1.f) | (alpha[1] < 1.f) | (alpha[2] < 1.f) | (alpha[3] < 1.f);
            if (__any(upd)) {
                #pragma unroll
                for (int dt = 0; dt < 8; ++dt)
                    #pragma unroll
                    for (int r = 0; r < 4; ++r) accO[rt][dt][r] *= alpha[r];
            }
            // P (C-layout) -> LDS for the C->A layout transform
            #pragma unroll
            for (int c = 0; c < 2; ++c)
                #pragma unroll
                for (int r = 0; r < 4; ++r)
                    pl[(rt * 16 + quad * 4 + r) * 40 + c * 16 + n16] = __float2bfloat16(sv[c][r]);
        }
        bf16x8_t pa[2];
        #pragma unroll
        for (int rt = 0; rt < 2; ++rt)
            pa[rt] = *reinterpret_cast<const bf16x8_t*>(&pl[(rt * 16 + n16) * 40 + quad * 8]);
        #pragma unroll
        for (int dt = 0; dt < 8; ++dt)
            #pragma unroll
            for (int rt = 0; rt < 2; ++rt)
                accO[rt][dt] = __builtin_amdgcn_mfma_f32_16x16x32_bf16(pa[rt], vf[dt], accO[rt][dt], 0, 0, 0);
    };

    // ping-pong K prefetch: load kt+1 while computing kt
    bf16x8_t kfA[2][4], kfB[2][4];
    load_k(kfA, 0);
    for (int kt = 0; kt <= ktmax; kt += 2) {
        int ktn = kt + 1 <= ktmax ? kt + 1 : ktmax;
        load_k(kfB, ktn);
        iter_body(kt, kfA);
        if (kt + 1 <= ktmax) {
            int ktn2 = kt + 2 <= ktmax ? kt + 2 : ktmax;
            load_k(kfA, ktn2);
            iter_body(kt + 1, kfB);
        }
    }

    #pragma unroll
    for (int rt = 0; rt < 2; ++rt) {
        float inv[4];
        #pragma unroll
        for (int r = 0; r < 4; ++r) inv[r] = 1.0f / l_[rt][r];
        #pragma unroll
        for (int dt = 0; dt < 8; ++dt)
            #pragma unroll
            for (int r = 0; r < 4; ++r) {
                int t = qrow0 + rt * 16 + quad * 4 + r;
                int col = h * HEAD_DIM + dt * 16 + n16;
                ctx[(size_t)t * Q_SZ + col] = __float2bfloat16(accO[rt][dt][r] * inv[r]);
            }
    }
}

extern "C" void kernel_launch(void* const* d_in, const int* in_sizes, int n_in,
                              void* d_out, int out_size, void* d_ws, size_t ws_size,
                              hipStream_t stream) {
    (void)in_sizes; (void)n_in; (void)out_size; (void)ws_size;
    const int*   positions = (const int*)d_in[0];
    const float* hidden    = (const float*)d_in[1];
    const float* w_qkv     = (const float*)d_in[2];
    const float* b_qkv     = (const float*)d_in[3];
    const float* w_dense   = (const float*)d_in[4];
    float* out = (float*)d_out;

    char* ws = (char*)d_ws;
    __hip_bfloat16* h_bf   = (__hip_bfloat16*)ws; ws += (size_t)T_SEQ * HIDDEN_SZ * 2;   // 16.8 MB (aliased by ctx later)
    __hip_bfloat16* wqkvT  = (__hip_bfloat16*)ws; ws += (size_t)QKV_DIM * HIDDEN_SZ * 2; // 37.7 MB
    __hip_bfloat16* wdT    = (__hip_bfloat16*)ws; ws += (size_t)HIDDEN_SZ * HIDDEN_SZ * 2; // 33.6 MB
    __hip_bfloat16* qkv_bf = (__hip_bfloat16*)ws; ws += (size_t)T_SEQ * QKV_DIM * 2;     // 18.9 MB
    __hip_bfloat16* q_bf   = (__hip_bfloat16*)ws; ws += (size_t)NUM_HEADS * T_SEQ * HEAD_DIM * 2; // 16.8 MB
    __hip_bfloat16* k_bf   = (__hip_bfloat16*)ws; ws += (size_t)KV_GROUPS * T_SEQ * HEAD_DIM * 2; // 1 MB
    __hip_bfloat16* vT_bf  = (__hip_bfloat16*)ws; ws += (size_t)KV_GROUPS * HEAD_DIM * T_SEQ * 2; // 1 MB
    __hip_bfloat16* ctx_bf = h_bf;  // h_bf dead after QKV GEMM; reuse for ctx

    // 1) hidden fp32 -> bf16
    convert_bf16_kernel<<<(T_SEQ * HIDDEN_SZ) / (256 * 4), 256, 0, stream>>>(hidden, h_bf, T_SEQ * HIDDEN_SZ);
    // 2) weights fp32 [K][N] -> bf16 [N][K]
    transpose_convert_kernel<<<dim3(QKV_DIM / 32, HIDDEN_SZ / 32), dim3(32, 8), 0, stream>>>(w_qkv, wqkvT, HIDDEN_SZ, QKV_DIM);
    transpose_convert_kernel<<<dim3(HIDDEN_SZ / 32, HIDDEN_SZ / 32), dim3(32, 8), 0, stream>>>(w_dense, wdT, HIDDEN_SZ, HIDDEN_SZ);
    // 3) QKV GEMM (+bias) -> bf16 qkv
    gemm_bf16_kernel<__hip_bfloat16><<<dim3(QKV_DIM / 128, T_SEQ / 128), 256, 0, stream>>>(
        h_bf, wqkvT, b_qkv, qkv_bf, T_SEQ, QKV_DIM, HIDDEN_SZ);
    // 4) RoPE + relayout (Q pre-scaled by rsqrt(128)*log2e)
    rope_reorg_kernel<<<dim3(T_SEQ, NUM_HEADS + 2 * KV_GROUPS), 64, 0, stream>>>(
        qkv_bf, positions, q_bf, k_bf, vT_bf);
    // 5) causal GQA flash attention -> ctx bf16 [t][h*128+d]
    flash_attn_kernel<<<dim3(T_SEQ / 128, NUM_HEADS), 256, 0, stream>>>(q_bf, k_bf, vT_bf, ctx_bf);
    // 6) dense GEMM -> fp32 out
    gemm_bf16_kernel<float><<<dim3(HIDDEN_SZ / 128, T_SEQ / 128), 256, 0, stream>>>(
        ctx_bf, wdT, nullptr, out, T_SEQ, HIDDEN_SZ, HIDDEN_SZ);
}